// Round 11
// baseline (206.874 us; speedup 1.0000x reference)
//
#include <hip/hip_runtime.h>

// Attention: qkv = x @ W^T + b ; causal MHA ; B=4 T=2048 C=1024 H=16 D=64
// R11 (cvt rewrite + gemm layout tweak; flash frozen from R9):
//  - cvt: LDS-transpose. R8-R10 cvt did 16B global accesses at 2-4KB strides
//    (~8x line amplification) -> ~65 us hidden cost (never in top-5!).
//    Now: block per 128x64 macro-tile; coalesced fp32 reads -> LDS ->
//    fragment-order 16B units written CONTIGUOUSLY (16KB/tile). Pure BW.
//  - gemm: tile internal order (ks, slot, u6) so each BK=32 stage is one
//    contiguous 4KB at base + kt32*4096 -> staging addresses strength-reduce
//    to a pointer increment (cuts the 67% VALUBusy address overhead).
//  - flash (R9-verified): 2-wave blocks, 2x16KB dbuf, tile-early DMA, fixed-m
//    softmax via raw v_exp_f32, l via MFMA-ones, XCD-local heads.
// Workspace (70 MB): xt@0 tiled x bf16 | wt@16M tiled W | qb@22M q bf16
//   [bh][t][d] *0.125*log2e | kvb@38M KV tiles 16KB/tile.
// Tile layout (xt/wt), within (bt,kt64) 8192-short tile, 8-short unit index
//   U = ks*512 + slot*64 + u6, slot = h*4 + i:
//   holds M[bt*128 + h*64 + i*16 + (u6&15)][kt64*64 + ks*32 + (u6>>4)*8 + 0..7]

typedef __attribute__((ext_vector_type(8))) short short8;
typedef __attribute__((ext_vector_type(4))) short s16x4;
typedef __attribute__((ext_vector_type(4))) float f32x4;

#define AS1 __attribute__((address_space(1)))
#define AS3 __attribute__((address_space(3)))

__device__ __forceinline__ unsigned short f2bf(float f) {
  unsigned int u = __float_as_uint(f);
  u += 0x7fffu + ((u >> 16) & 1u);
  return (unsigned short)(u >> 16);
}

__device__ __forceinline__ unsigned int pack_bf16(float lo, float hi) {
  return __builtin_amdgcn_perm(__float_as_uint(hi) + 0x8000u,
                               __float_as_uint(lo) + 0x8000u, 0x07060302u);
}

// async 16B/lane global->LDS; LDS dest = wave-uniform base + lane*16
__device__ __forceinline__ void async_copy16(const unsigned short* g, unsigned short* l) {
  const AS1 unsigned char* gp = (const AS1 unsigned char*)(unsigned long long)(uintptr_t)g;
  AS3 unsigned char* lp = (AS3 unsigned char*)(unsigned int)(uintptr_t)l;
  __builtin_amdgcn_global_load_lds((const AS1 void*)gp, (AS3 void*)lp, 16, 0, 0);
}

// ------------- fp32 -> bf16 convert via LDS transpose -----------------------
// Block = one 128x64 macro-tile. blk<1024: x (bt=blk>>4, kt=blk&15);
// else W (t=blk-1024). Phase1 coalesced fp32 reads -> bf16 -> LDS (stride 72).
// Phase2: fragment-order LDS reads -> contiguous 16KB global write.
__global__ __launch_bounds__(256) void cvt_both(const float* __restrict__ x,
                                                const float* __restrict__ W,
                                                unsigned short* __restrict__ xt,
                                                unsigned short* __restrict__ wt) {
  __shared__ unsigned short lds[128 * 72];
  const int tid = threadIdx.x;
  int blk = blockIdx.x;
  const float* in;
  unsigned short* outp;
  int bt, kt;
  if (blk < 1024) { in = x; outp = xt; bt = blk >> 4; kt = blk & 15; }
  else { blk -= 1024; in = W; outp = wt; bt = blk >> 4; kt = blk & 15; }
  const float* src = in + (size_t)(bt * 128) * 1024 + kt * 64;
  unsigned short* dst = outp + (size_t)(bt * 16 + kt) * 8192;

  // phase 1: 4 steps x (32 rows, 8 threads/row reading 2 float4)
  const int prow = tid >> 3, pcol = (tid & 7) * 8;
#pragma unroll
  for (int step = 0; step < 4; ++step) {
    int row = step * 32 + prow;
    const float4* p = (const float4*)(src + (size_t)row * 1024 + pcol);
    float4 a = p[0], b = p[1];
    uint4 o;
    o.x = pack_bf16(a.x, a.y);
    o.y = pack_bf16(a.z, a.w);
    o.z = pack_bf16(b.x, b.y);
    o.w = pack_bf16(b.z, b.w);
    *(uint4*)(&lds[row * 72 + pcol]) = o;
  }
  __syncthreads();

  // phase 2: 4 units/thread, U = u*256 + tid; decode (ks, slot, u6)
#pragma unroll
  for (int u = 0; u < 4; ++u) {
    int U = u * 256 + tid;
    int ks = U >> 9, slot = (U >> 6) & 7, u6 = U & 63;
    int srow = (slot >> 2) * 64 + (slot & 3) * 16 + (u6 & 15);
    int scol = ks * 32 + (u6 >> 4) * 8;
    uint4 v = *(const uint4*)(&lds[srow * 72 + scol]);
    *(uint4*)(dst + U * 8) = v;
  }
}

// ------------- QKV GEMM: BK=32 dbuf, contiguous-step staging ----------------
// 128x128 tile, 4 waves 2x2, wave 64x64 = 4x4 16x16x32 MFMA per kt32.
// LDS 2 x (8KB A + 8KB B) = 32KB. Stage for kt32 = contiguous 4KB A + 4KB B.
__global__ __launch_bounds__(256) void qkv_gemm(const unsigned short* __restrict__ xt,
                                                const unsigned short* __restrict__ wt,
                                                const float* __restrict__ bias,
                                                unsigned short* __restrict__ qb,
                                                unsigned short* __restrict__ kvb) {
  __shared__ unsigned short As[2][4096];
  __shared__ unsigned short Bs[2][4096];
  int tid = threadIdx.x;
  int wave = tid >> 6, lane = tid & 63;
  int q4 = lane >> 4, l16 = lane & 15;
  int bm = blockIdx.x, bn = blockIdx.y;

  f32x4 zero = {0.f, 0.f, 0.f, 0.f};
  f32x4 acc[4][4];
#pragma unroll
  for (int i = 0; i < 4; ++i)
#pragma unroll
    for (int j = 0; j < 4; ++j) acc[i][j] = zero;

  // per-lane staging source base: slot fi = wave*2 + j, unit offset fi*512+lane*8
  const unsigned short* ga0 = xt + (size_t)bm * 16 * 8192 + (wave * 2) * 512 + lane * 8;
  const unsigned short* gb0 = wt + (size_t)bn * 16 * 8192 + (wave * 2) * 512 + lane * 8;

  auto stage = [&](int d, int kt32) {
    const unsigned short* ga = ga0 + kt32 * 4096;
    const unsigned short* gb = gb0 + kt32 * 4096;
    int fb = wave * 2 * 512;
    async_copy16(ga, &As[d][fb]);
    async_copy16(ga + 512, &As[d][fb + 512]);
    async_copy16(gb, &Bs[d][fb]);
    async_copy16(gb + 512, &Bs[d][fb + 512]);
  };

  stage(0, 0);
  for (int kt = 0; kt < 32; ++kt) {
    __syncthreads();  // drains buf[kt&1]'s DMAs (issued a step ago)
    if (kt < 31) stage((kt + 1) & 1, kt + 1);
    const unsigned short* Ac = As[kt & 1];
    const unsigned short* Bc = Bs[kt & 1];
    short8 af[4], bf[4];
#pragma unroll
    for (int i = 0; i < 4; ++i)
      af[i] = *(const short8*)(Ac + ((wave & 1) * 4 + i) * 512 + lane * 8);
#pragma unroll
    for (int j = 0; j < 4; ++j)
      bf[j] = *(const short8*)(Bc + ((wave >> 1) * 4 + j) * 512 + lane * 8);
#pragma unroll
    for (int i = 0; i < 4; ++i)
#pragma unroll
      for (int j = 0; j < 4; ++j)
        acc[i][j] = __builtin_amdgcn_mfma_f32_16x16x32_bf16(af[i], bf[j], acc[i][j], 0, 0, 0);
  }

  // epilogue (R8-R10-verified): +bias; q *0.125*log2e; k,v -> pre-tiled kvb
  const float QSCALE = 0.18033688011112042f;
  int rowbase = bm * 128 + (wave & 1) * 64;
  int colbase = bn * 128 + (wave >> 1) * 64;
#pragma unroll
  for (int j = 0; j < 4; ++j) {
    int o = colbase + j * 16 + l16;
    float bv = bias[o];
#pragma unroll
    for (int i = 0; i < 4; ++i) {
      int r0 = rowbase + i * 16 + q4 * 4;
      int b = r0 >> 11, t0 = r0 & 2047;
      if (o < 1024) {
        int h = o >> 6, d = o & 63;
#pragma unroll
        for (int r = 0; r < 4; ++r)
          qb[((((size_t)b * 16 + h) * 2048 + t0 + r) << 6) + d] =
              f2bf((acc[i][j][r] + bv) * QSCALE);
      } else if (o < 2048) {
        int o2 = o - 1024;
        int h = o2 >> 6, dd = o2 & 63;
        int st = t0 >> 6, s6 = t0 & 63;
        int ns = s6 >> 4, l16p = s6 & 15;
        int ks = dd >> 5, q4p = (dd & 31) >> 3, jj = dd & 7;
        size_t base = ((size_t)(b * 16 + h) * 32 + st) * 8192 +
                      ((ns * 2 + ks) * 64 + q4p * 16 + l16p) * 8 + jj;
#pragma unroll
        for (int r = 0; r < 4; ++r)
          kvb[base + r * 8] = f2bf(acc[i][j][r] + bv);
      } else {
        int o3 = o - 2048;
        int h = o3 >> 6, dd = o3 & 63;
        int st = t0 >> 6, s6 = t0 & 63;
        int ns = s6 >> 4, q4p = (s6 >> 2) & 3;
        int p = dd >> 5, halfd = (dd >> 4) & 1, l16p = dd & 15;
        size_t base = ((size_t)(b * 16 + h) * 32 + st) * 8192 + 4096 +
                      ((ns * 2 + p) * 64 + q4p * 16 + l16p) * 8 + halfd * 4;
        ushort4 pk;
        pk.x = f2bf(acc[i][j][0] + bv);
        pk.y = f2bf(acc[i][j][1] + bv);
        pk.z = f2bf(acc[i][j][2] + bv);
        pk.w = f2bf(acc[i][j][3] + bv);
        *(ushort4*)(&kvb[base]) = pk;
      }
    }
  }
}

// ------------- Flash attention: XCD-local heads, raw exp2 (R9, frozen) ------
__global__ __launch_bounds__(128, 4) void flash_attn(const unsigned short* __restrict__ qb,
                                                     const unsigned short* __restrict__ kvb,
                                                     float* __restrict__ out) {
  __shared__ unsigned short buf[2][8192];

  const int tid = threadIdx.x;
  const int wave = tid >> 6, lane = tid & 63;
  const int q4 = lane >> 4, l16 = lane & 15;
  const int n = blockIdx.x;
  const int bh = (n & 7) * 8 + ((n >> 3) & 7);
  const int bx = n >> 6;
  const int b = bh >> 4, h = bh & 15;

  const unsigned short* Qg = qb + (size_t)bh * (2048 * 64);
  const unsigned short* KVg = kvb + (size_t)bh * 32 * 8192;
  const s16x4 ones = {(short)0x3F80, (short)0x3F80, (short)0x3F80, (short)0x3F80};

  auto stage = [&](int d, int st) {
    const unsigned short* tp = KVg + (size_t)st * 8192;
#pragma unroll
    for (int i2 = 0; i2 < 8; ++i2) {
      int u = i2 * 128 + wave * 64;
      async_copy16(tp + (u + lane) * 8, &buf[d][u * 8]);
    }
  };

  for (int pass = 0; pass < 2; ++pass) {
    const int qt = pass ? 31 - bx : bx;
    const int t0w = qt * 64 + wave * 32;

    short8 qf[2][2];
#pragma unroll
    for (int mt = 0; mt < 2; ++mt)
#pragma unroll
      for (int ks = 0; ks < 2; ++ks)
        qf[mt][ks] = *(const short8*)(Qg + (size_t)(t0w + mt * 16 + l16) * 64 +
                                      ks * 32 + q4 * 8);

    f32x4 zero = {0.f, 0.f, 0.f, 0.f};
    f32x4 oT[2][4];
#pragma unroll
    for (int mt = 0; mt < 2; ++mt)
#pragma unroll
      for (int nd = 0; nd < 4; ++nd) oT[mt][nd] = zero;
    f32x4 l_acc[2] = {zero, zero};

    __syncthreads();  // prior pass's reads done before restaging buf0
    stage(0, 0);
    for (int st = 0; st <= qt; ++st) {
      __syncthreads();  // drains buf[st&1] DMAs (issued a tile ago)
      if (st < qt) stage((st + 1) & 1, st + 1);
      const unsigned short* cur = buf[st & 1];

      f32x4 sT[2][4];
#pragma unroll
      for (int ns = 0; ns < 4; ++ns) {
        short8 kf0 = *(const short8*)(cur + (ns * 2 + 0) * 512 + lane * 8);
        short8 kf1 = *(const short8*)(cur + (ns * 2 + 1) * 512 + lane * 8);
#pragma unroll
        for (int mt = 0; mt < 2; ++mt) {
          sT[mt][ns] = __builtin_amdgcn_mfma_f32_16x16x32_bf16(kf0, qf[mt][0], zero, 0, 0, 0);
          sT[mt][ns] = __builtin_amdgcn_mfma_f32_16x16x32_bf16(kf1, qf[mt][1], sT[mt][ns], 0, 0, 0);
        }
      }

      if (st == qt) {  // diagonal: mask s > t; exp2(-3e38) = 0
#pragma unroll
        for (int mt = 0; mt < 2; ++mt) {
          int tg = t0w + mt * 16 + l16;
#pragma unroll
          for (int ns = 0; ns < 4; ++ns) {
            int sgb = st * 64 + ns * 16 + q4 * 4;
#pragma unroll
            for (int r = 0; r < 4; ++r)
              if (sgb + r > tg) sT[mt][ns][r] = -3.0e38f;
          }
        }
      }

#pragma unroll
      for (int ns = 0; ns < 4; ++ns) {
        s16x4 pf[2];
#pragma unroll
        for (int mt = 0; mt < 2; ++mt) {
          union { unsigned int u[2]; s16x4 s4; } pu;
          pu.u[0] = pack_bf16(__builtin_amdgcn_exp2f(sT[mt][ns][0]),
                              __builtin_amdgcn_exp2f(sT[mt][ns][1]));
          pu.u[1] = pack_bf16(__builtin_amdgcn_exp2f(sT[mt][ns][2]),
                              __builtin_amdgcn_exp2f(sT[mt][ns][3]));
          pf[mt] = pu.s4;
        }
#pragma unroll
        for (int p = 0; p < 2; ++p) {
          short8 v8 = *(const short8*)(cur + 4096 + ((ns * 2 + p) * 64 + lane) * 8);
          s16x4 vlo = __builtin_shufflevector(v8, v8, 0, 1, 2, 3);
          s16x4 vhi = __builtin_shufflevector(v8, v8, 4, 5, 6, 7);
#pragma unroll
          for (int mt = 0; mt < 2; ++mt) {
            oT[mt][2 * p] = __builtin_amdgcn_mfma_f32_16x16x16bf16_1k(vlo, pf[mt], oT[mt][2 * p], 0, 0, 0);
            oT[mt][2 * p + 1] = __builtin_amdgcn_mfma_f32_16x16x16bf16_1k(vhi, pf[mt], oT[mt][2 * p + 1], 0, 0, 0);
          }
        }
#pragma unroll
        for (int mt = 0; mt < 2; ++mt)
          l_acc[mt] = __builtin_amdgcn_mfma_f32_16x16x16bf16_1k(ones, pf[mt], l_acc[mt], 0, 0, 0);
      }
    }

#pragma unroll
    for (int mt = 0; mt < 2; ++mt) {
      float inv = 1.0f / l_acc[mt][0];
      int t = t0w + mt * 16 + l16;
      float* op = out + (size_t)(b * 2048 + t) * 1024 + h * 64 + q4 * 4;
#pragma unroll
      for (int nd = 0; nd < 4; ++nd) {
        float4 o4 = {oT[mt][nd][0] * inv, oT[mt][nd][1] * inv,
                     oT[mt][nd][2] * inv, oT[mt][nd][3] * inv};
        *(float4*)(op + nd * 16) = o4;
      }
    }
  }
}

extern "C" void kernel_launch(void* const* d_in, const int* in_sizes, int n_in,
                              void* d_out, int out_size, void* d_ws, size_t ws_size,
                              hipStream_t stream) {
  const float* x = (const float*)d_in[0];
  const float* W = (const float*)d_in[1];
  const float* bias = (const float*)d_in[2];
  float* out = (float*)d_out;

  char* ws = (char*)d_ws;
  unsigned short* xt = (unsigned short*)(ws);
  unsigned short* wt = (unsigned short*)(ws + 16777216);
  unsigned short* qb = (unsigned short*)(ws + 23068672);
  unsigned short* kvb = (unsigned short*)(ws + 39845888);

  hipLaunchKernelGGL(cvt_both, dim3(1408), dim3(256), 0, stream, x, W, xt, wt);
  hipLaunchKernelGGL(qkv_gemm, dim3(64, 24), dim3(256), 0, stream, xt, wt, bias,
                     qb, kvb);
  hipLaunchKernelGGL(flash_attn, dim3(1024), dim3(128), 0, stream, qb, kvb, out);
}